// Round 1
// 485.515 us; speedup vs baseline: 1.2011x; 1.2011x over previous
//
#include <hip/hip_runtime.h>

// CRF forward, latency-optimized v2: FOUR WAVES per sequence (256 thr/block),
// splitting the 128x128 exp-domain matvec across all 4 SIMDs of the CU.
// Row r = 32*wid + (lane&31); column half = lane>>5 (64 cols each).
// Per step per lane: 8 uniform-ish ds_read_b128 of a (2-addr broadcast, free),
// 32 v_dot2_f32_f16 in 4 chains of 8, one v_permlane32_swap_b32 cross-half
// combine, scale+cvt+dup-write of a, DPP max tree (parallel with the write
// chain). Cross-wave sync: ONE raw barrier per step via inline asm
//   s_waitcnt lgkmcnt(0); s_barrier      (NO vmcnt drain -> the 4-step-deep
// global logit prefetch stays in flight across barriers).
// Normalizer: same 1-step-stale power-of-2 feedback as v1 (P = Em - P + 6),
// with per-wave maxes exchanged through a parity ring in LDS and combined in
// the next step's LDS-latency shadow. Kacc integer side chain is exact.

typedef _Float16 half_t;
typedef _Float16 h2 __attribute__((ext_vector_type(2)));
typedef _Float16 h8 __attribute__((ext_vector_type(8)));

#define TB  1024
#define NUM 126
#define LBL 128

__device__ __forceinline__ float dot2f(h2 a, h2 b, float c) {
  return __builtin_amdgcn_fdot2(a, b, c, false);
}

template <int U>
__device__ __forceinline__ float dotu(h8 a, h8 e, float c) {
  return dot2f(__builtin_shufflevector(a, a, 2 * U, 2 * U + 1),
               __builtin_shufflevector(e, e, 2 * U, 2 * U + 1), c);
}

template <int CTRL>
__device__ __forceinline__ float dpp_max_step(float x) {
  int xi = __float_as_int(x);
  int yi = __builtin_amdgcn_update_dpp(xi, xi, CTRL, 0xF, 0xF, false);
  return fmaxf(x, __int_as_float(yi));
}

// After this tree, lanes 32..63 (in particular lane 63) hold the wave max.
__device__ __forceinline__ float wave_max_tree(float x) {
  x = dpp_max_step<0x111>(x);  // row_shr:1
  x = dpp_max_step<0x112>(x);  // row_shr:2
  x = dpp_max_step<0x114>(x);  // row_shr:4
  x = dpp_max_step<0x118>(x);  // row_shr:8
  x = dpp_max_step<0x142>(x);  // row_bcast:15
  x = dpp_max_step<0x143>(x);  // row_bcast:31
  return x;
}

__device__ __forceinline__ float wave_max64(float x) {
  return __int_as_float(
      __builtin_amdgcn_readlane(__float_as_int(wave_max_tree(x)), 63));
}

// lane l gets x[l] + x[l^32] (cross-half sum), 1 VALU op + 1 add.
// v_permlane32_swap_b32 a, b : a' = [a.lo, b.lo], b' = [a.hi, b.hi].
__device__ __forceinline__ float half_sum(float x) {
  int a = __float_as_int(x), b = __float_as_int(x);
  asm("v_permlane32_swap_b32 %0, %1" : "+v"(a), "+v"(b));
  return __int_as_float(a) + __int_as_float(b);
}

__global__ __launch_bounds__(256, 1)
void crf_fwd(const float* __restrict__ logits, const int* __restrict__ labels,
             const int* __restrict__ lens, const float* __restrict__ trans,
             float* __restrict__ out)
{
  const int b    = blockIdx.x;
  const int tid  = threadIdx.x;
  const int wid  = tid >> 6;                    // wave 0..3
  const int l    = tid & 63;                    // lane 0..63
  const int half = l >> 5;                      // column half 0/1
  const int r    = (wid << 5) + (l & 31);       // output state/row 0..127
  const int rr   = (r < NUM) ? r : (NUM - 1);   // clamped row for logit loads
  const float rmask = (r < NUM) ? 1.0f : 0.0f;  // start/end rows dead
  const int len  = lens[b];

  __shared__ __align__(16) h2    a_sh[2][64];   // a[parity], h16 state s at idx s
  __shared__ __align__(16) float maxsh[2][4];   // per-wave maxes, parity ring
  __shared__ float goldsh[4], Msh[4], psh[4];

  const float* lgbase = logits + (size_t)b * TB * NUM;
  const int*   lab    = labels + (size_t)b * TB;

  // ---- E = exp(trans) fragment: row r, columns half*64 .. half*64+63 (f16)
  h8 E[8];
  {
    const float* tr = trans + r * LBL + half * 64;
    #pragma unroll
    for (int q = 0; q < 8; ++q) {
      h8 v;
      #pragma unroll
      for (int e = 0; e < 8; ++e) v[e] = (half_t)__expf(tr[8 * q + e]);
      E[q] = v;
    }
  }

  // ---- gold score (one-time, 256 threads)
  float g = 0.f;
  #pragma unroll
  for (int kk = 0; kk < 4; ++kk) {
    int t = tid + 256 * kk;
    if (t < len) {
      int lt = lab[t];
      int lp = (t == 0) ? (LBL - 2) : lab[t - 1];   // start state = 126
      g += lgbase[(size_t)t * NUM + lt] + trans[lt * LBL + lp];
    }
  }
  if (tid == 0) g += trans[(LBL - 1) * LBL + lab[len - 1]];  // -> end
  #pragma unroll
  for (int o = 1; o < 64; o <<= 1) g += __shfl_xor(g, o);
  if (l == 0) goldsh[wid] = g;

  // ---- a_0 = one-hot(start=126); prime max ring so P_1 = 6
  if (tid < 64) {
    h2 ai;
    ai[0] = (half_t)((2 * tid     == LBL - 2) ? 1.0f : 0.0f);
    ai[1] = (half_t)((2 * tid + 1 == LBL - 2) ? 1.0f : 0.0f);
    a_sh[0][tid] = ai;
  }
  if (tid < 8) maxsh[tid >> 2][tid & 3] = 64.0f;  // Em = 6 primer
  __syncthreads();

  // ---- logit prefetch, 4 rows deep (1 load/lane/step)
  float plg[4];
  #pragma unroll
  for (int d = 0; d < 4; ++d) plg[d] = lgbase[(size_t)d * NUM + rr];

  int P = 6, Kacc = 0, Kout = 0, par = 0;
  float w_out = 1.f;

#define STEP_BODY(Q)                                                        \
  {                                                                         \
    /* head (runs in LDS-latency shadow): max combine + P update + exp */   \
    const float4 mv = *(const float4*)(&maxsh[par][0]);                     \
    const h8* ap = (const h8*)(&a_sh[par][0]) + half * 8;                   \
    float eL = __expf(Q) * rmask;                                           \
    float s0 = 0.f, s1 = 0.f, s2 = 0.f, s3 = 0.f;                           \
    _Pragma("unroll")                                                       \
    for (int q = 0; q < 8; q += 2) {                                        \
      h8 avA = ap[q], avB = ap[q + 1];                                      \
      h8 eA = E[q], eB = E[q + 1];                                          \
      s0 = dotu<0>(avA, eA, s0);  s1 = dotu<1>(avA, eA, s1);                \
      s2 = dotu<2>(avA, eA, s2);  s3 = dotu<3>(avA, eA, s3);                \
      s0 = dotu<0>(avB, eB, s0);  s1 = dotu<1>(avB, eB, s1);                \
      s2 = dotu<2>(avB, eB, s2);  s3 = dotu<3>(avB, eB, s3);                \
    }                                                                       \
    float mm = fmaxf(fmaxf(mv.x, mv.y), fmaxf(mv.z, mv.w));                 \
    P = (((__float_as_int(mm) >> 23) & 0xFF) - 127) - P + 6;                \
    /* tail: combine halves, scale, store; max tree runs in parallel */     \
    float ssum = half_sum((s0 + s1) + (s2 + s3));                           \
    float w = ssum * eL;                                                    \
    float sc = __int_as_float((127 - P) << 23);   /* 2^-P, EXACT */         \
    ((half_t*)(&a_sh[par ^ 1][0]))[r] = (half_t)(w * sc);  /* dup-write */  \
    Kout = Kacc;  Kacc += P;                      /* SALU side chain */     \
    float m = wave_max_tree(w);                                             \
    if (l == 63) maxsh[par ^ 1][wid] = m;                                   \
    /* LDS-only drain + barrier: global prefetches stay in flight */        \
    asm volatile("s_waitcnt lgkmcnt(0)\n\ts_barrier" ::: "memory");         \
    w_out = w;  par ^= 1;                                                   \
  }

  int t = 0;
  for (; t + 4 <= len; t += 4) {
    int q0 = t + 4, q1 = t + 5, q2 = t + 6, q3 = t + 7;
    q0 = (q0 < TB) ? q0 : (TB - 1);  q1 = (q1 < TB) ? q1 : (TB - 1);
    q2 = (q2 < TB) ? q2 : (TB - 1);  q3 = (q3 < TB) ? q3 : (TB - 1);
    STEP_BODY(plg[0])
    plg[0] = lgbase[(size_t)q0 * NUM + rr];
    STEP_BODY(plg[1])
    plg[1] = lgbase[(size_t)q1 * NUM + rr];
    STEP_BODY(plg[2])
    plg[2] = lgbase[(size_t)q2 * NUM + rr];
    STEP_BODY(plg[3])
    plg[3] = lgbase[(size_t)q3 * NUM + rr];
  }
  const int rem = len - t;
  if (rem > 0) STEP_BODY(plg[0])
  if (rem > 1) STEP_BODY(plg[1])
  if (rem > 2) STEP_BODY(plg[2])
#undef STEP_BODY

  // ---- alpha_len[r] = Kout*ln2 + log(w_len[r]); norm = logsumexp(+trans_end)
  const float LN2 = 0.6931471805599453f;
  float v = (float)Kout * LN2 + __logf(w_out) + trans[(LBL - 1) * LBL + r];
  if (half) v = -__builtin_inff();          // dedupe the 2-lanes-per-row copies
  float M = wave_max64(v);
  float p = __expf(v - M);                  // -inf -> 0
  #pragma unroll
  for (int o = 1; o < 64; o <<= 1) p += __shfl_xor(p, o);
  if (l == 0) { Msh[wid] = M; psh[wid] = p; }
  __syncthreads();
  if (tid == 0) {
    float gT = goldsh[0] + goldsh[1] + goldsh[2] + goldsh[3];
    float Mg = fmaxf(fmaxf(Msh[0], Msh[1]), fmaxf(Msh[2], Msh[3]));
    float pg = psh[0] * __expf(Msh[0] - Mg) + psh[1] * __expf(Msh[1] - Mg)
             + psh[2] * __expf(Msh[2] - Mg) + psh[3] * __expf(Msh[3] - Mg);
    out[b] = gT - (Mg + __logf(pg));
  }
}

extern "C" void kernel_launch(void* const* d_in, const int* in_sizes, int n_in,
                              void* d_out, int out_size, void* d_ws, size_t ws_size,
                              hipStream_t stream) {
  const float* logits = (const float*)d_in[0];
  const int*   labels = (const int*)d_in[1];
  const int*   lens   = (const int*)d_in[2];
  const float* trans  = (const float*)d_in[3];
  float* out = (float*)d_out;
  (void)in_sizes; (void)n_in; (void)out_size; (void)d_ws; (void)ws_size;
  crf_fwd<<<256, 256, 0, stream>>>(logits, labels, lens, trans, out);
}

// Round 2
// 482.091 us; speedup vs baseline: 1.2096x; 1.0071x over previous
//
#include <hip/hip_runtime.h>

// CRF forward v3: 4 waves/seq, rows-per-lane R=2, cols-per-lane C=32.
// v2's bottleneck was the shared per-CU LDS return pipe: broadcasting the
// 256 B alpha vector as 128 B/lane to 256 lanes = 32 KB/step (~384 cyc).
// v3 halves delivered bytes (16 KB/step) by giving each lane TWO adjacent
// rows over one column-quarter (reads 64 B/step), and combines the 4
// quarter-partials per row with two pure-VALU DPP quad_perm add stages
// (quarter index lives in lane bits [1:0] so the combine never touches the
// LDS pipe). Logit loads for the row pair merge into one aligned float2.
// Sync: one "s_waitcnt lgkmcnt(0); s_barrier" per step (NO vmcnt drain ->
// 4-deep global logit prefetch stays in flight). Normalizer: stale
// power-of-2 feedback P = Em - P + 6 with per-wave maxes in a parity ring;
// Kacc integer side chain exact.

typedef _Float16 half_t;
typedef _Float16 h2 __attribute__((ext_vector_type(2)));
typedef _Float16 h8 __attribute__((ext_vector_type(8)));

#define TB  1024
#define NUM 126
#define LBL 128

__device__ __forceinline__ float dot2f(h2 a, h2 b, float c) {
  return __builtin_amdgcn_fdot2(a, b, c, false);
}

template <int U>
__device__ __forceinline__ float dotu(h8 a, h8 e, float c) {
  return dot2f(__builtin_shufflevector(a, a, 2 * U, 2 * U + 1),
               __builtin_shufflevector(e, e, 2 * U, 2 * U + 1), c);
}

template <int CTRL>
__device__ __forceinline__ float dpp_max_step(float x) {
  int xi = __float_as_int(x);
  int yi = __builtin_amdgcn_update_dpp(xi, xi, CTRL, 0xF, 0xF, false);
  return fmaxf(x, __int_as_float(yi));
}

// After this tree, lane 63 holds the wave max.
__device__ __forceinline__ float wave_max_tree(float x) {
  x = dpp_max_step<0x111>(x);  // row_shr:1
  x = dpp_max_step<0x112>(x);  // row_shr:2
  x = dpp_max_step<0x114>(x);  // row_shr:4
  x = dpp_max_step<0x118>(x);  // row_shr:8
  x = dpp_max_step<0x142>(x);  // row_bcast:15
  x = dpp_max_step<0x143>(x);  // row_bcast:31
  return x;
}

__device__ __forceinline__ float wave_max64(float x) {
  return __int_as_float(
      __builtin_amdgcn_readlane(__float_as_int(wave_max_tree(x)), 63));
}

template <int CTRL>
__device__ __forceinline__ float dpp_add_step(float x) {
  int xi = __float_as_int(x);
  int yi = __builtin_amdgcn_update_dpp(xi, xi, CTRL, 0xF, 0xF, false);
  return x + __int_as_float(yi);
}

// Sum over the 4 lanes of each quad (pure VALU, no LDS pipe):
// quad_perm{1,0,3,2}=0xB1 (xor1), quad_perm{2,3,0,1}=0x4E (xor2).
__device__ __forceinline__ float quad_sum(float x) {
  x = dpp_add_step<0xB1>(x);
  x = dpp_add_step<0x4E>(x);
  return x;
}

__global__ __launch_bounds__(256, 1)
void crf_fwd(const float* __restrict__ logits, const int* __restrict__ labels,
             const int* __restrict__ lens, const float* __restrict__ trans,
             float* __restrict__ out)
{
  const int b   = blockIdx.x;
  const int tid = threadIdx.x;
  const int wid = tid >> 6;                 // wave 0..3
  const int l   = tid & 63;                 // lane 0..63
  const int q   = l & 3;                    // column quarter 0..3
  const int p   = l >> 2;                   // row-pair 0..15
  const int r0  = (wid << 5) + (p << 1);    // even row 0..126
  const int r1  = r0 + 1;                   // odd row
  const float rm0 = (r0 < NUM) ? 1.0f : 0.0f;   // rows 126,127 dead
  const float rm1 = (r1 < NUM) ? 1.0f : 0.0f;
  const int rre = (r0 < NUM - 1) ? r0 : (NUM - 2);  // even clamp: float2-safe
  const int len = lens[b];

  __shared__ __align__(16) h2    a_sh[2][64];   // a[parity]; idx s = (a[2s],a[2s+1])
  __shared__ __align__(16) float maxsh[2][4];   // per-wave maxes, parity ring
  __shared__ float goldsh[4], Msh[4], psh[4];

  const float* lgbase = logits + (size_t)b * TB * NUM;
  const int*   lab    = labels + (size_t)b * TB;

  // ---- E = exp(trans) fragments: rows r0,r1, cols q*32 .. q*32+31 (f16)
  h8 E0[4], E1[4];
  {
    const float* t0 = trans + r0 * LBL + q * 32;
    const float* t1 = trans + r1 * LBL + q * 32;
    #pragma unroll
    for (int c = 0; c < 4; ++c) {
      h8 v0, v1;
      #pragma unroll
      for (int e = 0; e < 8; ++e) {
        v0[e] = (half_t)__expf(t0[8 * c + e]);
        v1[e] = (half_t)__expf(t1[8 * c + e]);
      }
      E0[c] = v0; E1[c] = v1;
    }
  }

  // ---- gold score (one-time, 256 threads)
  float g = 0.f;
  #pragma unroll
  for (int kk = 0; kk < 4; ++kk) {
    int t = tid + 256 * kk;
    if (t < len) {
      int lt = lab[t];
      int lp = (t == 0) ? (LBL - 2) : lab[t - 1];   // start state = 126
      g += lgbase[(size_t)t * NUM + lt] + trans[lt * LBL + lp];
    }
  }
  if (tid == 0) g += trans[(LBL - 1) * LBL + lab[len - 1]];  // -> end
  #pragma unroll
  for (int o = 1; o < 64; o <<= 1) g += __shfl_xor(g, o);
  if (l == 0) goldsh[wid] = g;

  // ---- a_0 = one-hot(start=126); prime max ring so P_1 = 6
  if (tid < 64) {
    h2 ai;
    ai[0] = (half_t)((2 * tid     == LBL - 2) ? 1.0f : 0.0f);
    ai[1] = (half_t)((2 * tid + 1 == LBL - 2) ? 1.0f : 0.0f);
    a_sh[0][tid] = ai;
  }
  if (tid < 8) maxsh[tid >> 2][tid & 3] = 64.0f;  // Em = 6 primer
  __syncthreads();

  // ---- logit prefetch, 4 rows deep; one aligned float2 per step (rows r0,r1)
  float2 plg[4];
  #pragma unroll
  for (int d = 0; d < 4; ++d)
    plg[d] = *(const float2*)(lgbase + (size_t)d * NUM + rre);

  int P = 6, Kacc = 0, Kout = 0, par = 0;
  float w0_out = 1.f, w1_out = 1.f;

#define DOT8(acc, av, ev)                                                   \
    acc = dotu<0>(av, ev, acc); acc = dotu<1>(av, ev, acc);                 \
    acc = dotu<2>(av, ev, acc); acc = dotu<3>(av, ev, acc);

#define STEP_BODY(Qv)                                                      \
  {                                                                        \
    const float4 mv = *(const float4*)(&maxsh[par][0]);                    \
    const h8* ap = (const h8*)(&a_sh[par][0]) + q * 4;                     \
    float eL0 = __expf((Qv).x) * rm0;                                      \
    float eL1 = __expf((Qv).y) * rm1;                                      \
    h8 av0 = ap[0], av1 = ap[1], av2 = ap[2], av3 = ap[3];                 \
    float sA = 0.f, sB = 0.f, sC = 0.f, sD = 0.f;                          \
    DOT8(sA, av0, E0[0])  DOT8(sC, av0, E1[0])                             \
    DOT8(sA, av1, E0[1])  DOT8(sC, av1, E1[1])                             \
    DOT8(sB, av2, E0[2])  DOT8(sD, av2, E1[2])                             \
    DOT8(sB, av3, E0[3])  DOT8(sD, av3, E1[3])                             \
    float mm = fmaxf(fmaxf(mv.x, mv.y), fmaxf(mv.z, mv.w));                \
    P = (((__float_as_int(mm) >> 23) & 0xFF) - 127) - P + 6;               \
    float w0 = quad_sum(sA + sB) * eL0;                                    \
    float w1 = quad_sum(sC + sD) * eL1;                                    \
    float sc = __int_as_float((127 - P) << 23);   /* 2^-P, EXACT */        \
    h2 pk;                                                                 \
    pk[0] = (half_t)(w0 * sc);                                             \
    pk[1] = (half_t)(w1 * sc);                                             \
    if (q == 0) a_sh[par ^ 1][(wid << 4) + p] = pk;                        \
    Kout = Kacc;  Kacc += P;                      /* SALU side chain */    \
    float m = wave_max_tree(fmaxf(w0, w1));                                \
    if (l == 63) maxsh[par ^ 1][wid] = m;                                  \
    /* LDS-only drain + barrier: global prefetches stay in flight */       \
    asm volatile("s_waitcnt lgkmcnt(0)\n\ts_barrier" ::: "memory");        \
    w0_out = w0;  w1_out = w1;  par ^= 1;                                  \
  }

  int t = 0;
  for (; t + 4 <= len; t += 4) {
    int q0 = t + 4, q1 = t + 5, q2 = t + 6, q3 = t + 7;
    q0 = (q0 < TB) ? q0 : (TB - 1);  q1 = (q1 < TB) ? q1 : (TB - 1);
    q2 = (q2 < TB) ? q2 : (TB - 1);  q3 = (q3 < TB) ? q3 : (TB - 1);
    STEP_BODY(plg[0])
    plg[0] = *(const float2*)(lgbase + (size_t)q0 * NUM + rre);
    STEP_BODY(plg[1])
    plg[1] = *(const float2*)(lgbase + (size_t)q1 * NUM + rre);
    STEP_BODY(plg[2])
    plg[2] = *(const float2*)(lgbase + (size_t)q2 * NUM + rre);
    STEP_BODY(plg[3])
    plg[3] = *(const float2*)(lgbase + (size_t)q3 * NUM + rre);
  }
  const int rem = len - t;
  if (rem > 0) STEP_BODY(plg[0])
  if (rem > 1) STEP_BODY(plg[1])
  if (rem > 2) STEP_BODY(plg[2])
#undef STEP_BODY
#undef DOT8

  // ---- alpha_len[r] = Kout*ln2 + log(w_len[r]); norm = logsumexp(+trans_end)
  const float LN2 = 0.6931471805599453f;
  float K = (float)Kout * LN2;
  float v0 = K + __logf(w0_out) + trans[(LBL - 1) * LBL + r0];
  float v1 = K + __logf(w1_out) + trans[(LBL - 1) * LBL + r1];
  if (q != 0) { v0 = -__builtin_inff(); v1 = -__builtin_inff(); }  // dedupe quads
  float M = wave_max64(fmaxf(v0, v1));
  float pp = __expf(v0 - M) + __expf(v1 - M);   // -inf -> 0
  #pragma unroll
  for (int o = 1; o < 64; o <<= 1) pp += __shfl_xor(pp, o);
  if (l == 0) { Msh[wid] = M; psh[wid] = pp; }
  __syncthreads();
  if (tid == 0) {
    float gT = goldsh[0] + goldsh[1] + goldsh[2] + goldsh[3];
    float Mg = fmaxf(fmaxf(Msh[0], Msh[1]), fmaxf(Msh[2], Msh[3]));
    float pg = psh[0] * __expf(Msh[0] - Mg) + psh[1] * __expf(Msh[1] - Mg)
             + psh[2] * __expf(Msh[2] - Mg) + psh[3] * __expf(Msh[3] - Mg);
    out[b] = gT - (Mg + __logf(pg));
  }
}

extern "C" void kernel_launch(void* const* d_in, const int* in_sizes, int n_in,
                              void* d_out, int out_size, void* d_ws, size_t ws_size,
                              hipStream_t stream) {
  const float* logits = (const float*)d_in[0];
  const int*   labels = (const int*)d_in[1];
  const int*   lens   = (const int*)d_in[2];
  const float* trans  = (const float*)d_in[3];
  float* out = (float*)d_out;
  (void)in_sizes; (void)n_in; (void)out_size; (void)d_ws; (void)ws_size;
  crf_fwd<<<256, 256, 0, stream>>>(logits, labels, lens, trans, out);
}